// Round 17
// baseline (258.021 us; speedup 1.0000x reference)
//
#include <hip/hip_runtime.h>
#include <cstdint>
#include <cmath>

// Fused Bayesian LSTM: B=4096, T=200, IN=79, H=10 (gates G=40)
// 8 rows per wave (64-thr block), 8 lanes per row: lane ii=lane&7 owns the
// 5 gates (type ty=ii&3, units hf*5..hf*5+4, hf=ii>>2) of row rr=lane>>3.
// Per 16-step window: 8x MFMA produce (R16-proven tile, counted vmcnt(5)
// stage pipeline) -> rec 16 steps (quad-DPP combine, quad-bcast + xor-4
// ds_swizzle h exchange; NO readlane). exp2 numerics proven in R12/R16.
// ws float layout (from prep):
//  [0,48)      bias*sA f32, gates 0..39, zero-padded to 48
//  [48,448)    Whh_hat f32 natural: 48 + k*40 + c
//  [512,2816)  Bh: bf16(sA*W) ushort[48][96], c-major (c*96+k), zero-pad
//  [2816,5120) Bl: bf16(sA*W - float(Bh)) same layout
#define Bsz 4096
#define Tlen 200
#define INs 79
#define Hs 10
#define Gs 40
#define LOG2E 1.4426950408889634f

typedef __attribute__((ext_vector_type(8))) short bf16x8;
typedef __attribute__((ext_vector_type(4))) float f32x4;

__device__ __forceinline__ unsigned short f2bf(float x) {   // RNE f32->bf16
    unsigned u = __float_as_uint(x);
    return (unsigned short)((u + 0x7FFF + ((u >> 16) & 1)) >> 16);
}

__global__ void prep_kernel(const float* __restrict__ wih_mu, const float* __restrict__ wih_rho, const float* __restrict__ wih_eps,
                            const float* __restrict__ whh_mu, const float* __restrict__ whh_rho, const float* __restrict__ whh_eps,
                            const float* __restrict__ b_mu,   const float* __restrict__ b_rho,   const float* __restrict__ b_eps,
                            float* __restrict__ w) {
    int idx = blockIdx.x * 256 + threadIdx.x;
    if (idx < 4608) {                       // sA*Wih -> Bh/Bl split, [48][96] c-major
        int c = idx / 96, k = idx % 96;
        float val = 0.0f;
        if (c < Gs && k < INs) {
            int s = k * Gs + c;
            float r = wih_rho[s];
            float sp = (r > 20.0f) ? r : log1pf(expf(r));
            val = fmaf(sp, wih_eps[s], wih_mu[s]);
            val *= (c >= 20 && c < 30) ? -2.0f : -1.0f;   // fold sA (exact)
        }
        unsigned short h = f2bf(val);
        float back = __uint_as_float((unsigned)h << 16);
        unsigned short l = f2bf(val - back);
        ((unsigned short*)(w + 512))[idx]  = h;
        ((unsigned short*)(w + 2816))[idx] = l;
    } else if (idx < 5008) {                // Whh f32 natural
        int m = idx - 4608;
        float r = whh_rho[m];
        float sp = (r > 20.0f) ? r : log1pf(expf(r));
        w[48 + m] = fmaf(sp, whh_eps[m], whh_mu[m]);
    } else if (idx < 5056) {                // sA*bias f32, padded to 48
        int m = idx - 5008;
        float val = 0.0f;
        if (m < Gs) {
            float r = b_rho[m];
            float sp = (r > 20.0f) ? r : log1pf(expf(r));
            val = fmaf(sp, b_eps[m], b_mu[m]);
            val *= (m >= 20 && m < 30) ? -2.0f : -1.0f;   // fold sA (exact)
        }
        w[m] = val;
    }
}

__global__ __launch_bounds__(64) void fused_kernel(
    const float* __restrict__ x, const float* __restrict__ w,
    const float* __restrict__ lin_w, const float* __restrict__ lin_b,
    float* __restrict__ out) {
    __shared__ __align__(16) float xb[2][1280];       // 16t x 79 staging, dbuf
    __shared__ __align__(16) float gbuf[8 * 676];     // per-row [16][42], stride 676

    const int lane = threadIdx.x;
    const int b0 = blockIdx.x * 8;

    // ---- MFMA produce mapping (R16-proven) ----
    const int jj = lane & 15;
    const int kg8 = (lane >> 4) * 8;
    const unsigned short* Bh = (const unsigned short*)(w + 512);
    const unsigned short* Bl = (const unsigned short*)(w + 2816);
    float bias3[3];
#pragma unroll
    for (int n = 0; n < 3; ++n) bias3[n] = w[n * 16 + jj];

    // ---- rec mapping: 8 lanes per row ----
    const int rr = lane >> 3;                 // row 0..7
    const int ii = lane & 7;
    const int ty = ii & 3;                    // 0=i,1=f,2=g,3=o
    const int hf = ii >> 2;                   // half: units hf*5..hf*5+4
    const int colb = ty * 10 + hf * 5;        // first gate col of this lane
    const float sAL = ((ty == 2) ? -2.0f : -1.0f) * LOG2E;
    const float sM  = (ty == 2) ? (-4.0f * LOG2E) : 1.0f;
    const float sC  = (ty == 2) ? ( 2.0f * LOG2E) : 0.0f;
    float wo[5][5], wx[5][5];                 // Whh cols, own-half / other-half h
#pragma unroll
    for (int qp = 0; qp < 5; ++qp)
#pragma unroll
        for (int q = 0; q < 5; ++q) {
            wo[qp][q] = w[48 + (hf * 5 + q) * Gs + colb + qp] * sAL;
            wx[qp][q] = w[48 + ((1 - hf) * 5 + q) * Gs + colb + qp] * sAL;
        }
    float ho[5], hx[5], C[5];
#pragma unroll
    for (int q = 0; q < 5; ++q) { ho[q] = 0.0f; hx[q] = 0.0f; C[q] = 0.0f; }

    const long xendB = (long)Bsz * Tlen * INs * 4 - 16;
    auto stage = [&](int r8, int t0, int buf) {   // 16 rows x 79 f32 = 316 slots, 5 vm instrs
        long srcB = ((long)(b0 + r8) * Tlen + t0) * (long)INs * 4;
        auto* ldsc = (__attribute__((address_space(3))) char*)&xb[buf][0];
#pragma unroll
        for (int kk = 0; kk < 4; ++kk) {
            long off = srcB + (long)(kk * 64 + lane) * 16;
            if (off > xendB) off = xendB;
            __builtin_amdgcn_global_load_lds(
                (const __attribute__((address_space(1))) void*)((const char*)x + off),
                (__attribute__((address_space(3))) void*)(ldsc + (kk * 64 + lane) * 16), 16, 0, 0);
        }
        {
            long off = srcB + (long)(256 + lane) * 16;
            if (off > xendB) off = xendB;
            if (lane < 60)
                __builtin_amdgcn_global_load_lds(
                    (const __attribute__((address_space(1))) void*)((const char*)x + off),
                    (__attribute__((address_space(3))) void*)(ldsc + (256 + lane) * 16), 16, 0, 0);
        }
    };

    auto produce = [&](const float* xbuf, float* gb) {   // R16-proven tile
        float f0[8], f1[8], f2[8];
#pragma unroll
        for (int e = 0; e < 8; ++e) f0[e] = xbuf[jj * INs + kg8 + e];
#pragma unroll
        for (int e = 0; e < 8; ++e) f1[e] = xbuf[jj * INs + 32 + kg8 + e];
#pragma unroll
        for (int e = 0; e < 8; ++e) {
            float raw = xbuf[jj * INs + 64 + kg8 + e];
            f2[e] = (kg8 + e < 15) ? raw : 0.0f;         // K-pad -> exact 0
        }
        asm volatile("s_waitcnt lgkmcnt(0)" ::: "memory");
        union { unsigned u[4]; bf16x8 v; } Ah[3], Al[3];
        const float* fp[3] = {f0, f1, f2};
#pragma unroll
        for (int ks = 0; ks < 3; ++ks) {
#pragma unroll
            for (int p = 0; p < 4; ++p) {
                float a = fp[ks][2 * p], bb = fp[ks][2 * p + 1];
                unsigned ua = __float_as_uint(a), ub = __float_as_uint(bb);
                Ah[ks].u[p] = __builtin_amdgcn_perm(ub, ua, 0x07060302);  // {hi(b),hi(a)}
                float ra = a  - __uint_as_float(ua & 0xFFFF0000u);        // exact
                float rb = bb - __uint_as_float(ub & 0xFFFF0000u);
                unsigned pk;
                asm("v_cvt_pk_bf16_f32 %0, %1, %2" : "=v"(pk) : "v"(ra), "v"(rb));
                Al[ks].u[p] = pk;
            }
        }
        f32x4 acc[3];
#pragma unroll
        for (int n = 0; n < 3; ++n)
            acc[n] = (f32x4){bias3[n], bias3[n], bias3[n], bias3[n]};
#pragma unroll
        for (int ks = 0; ks < 3; ++ks) {
            const int k0 = ks * 32;
#pragma unroll
            for (int n = 0; n < 3; ++n) {
                int boff = (n * 16 + jj) * 96 + k0 + kg8;
                bf16x8 bh = *(const bf16x8*)(Bh + boff);
                bf16x8 bl = *(const bf16x8*)(Bl + boff);
                acc[n] = __builtin_amdgcn_mfma_f32_16x16x32_bf16(Ah[ks].v, bh, acc[n], 0, 0, 0);
                acc[n] = __builtin_amdgcn_mfma_f32_16x16x32_bf16(Ah[ks].v, bl, acc[n], 0, 0, 0);
                acc[n] = __builtin_amdgcn_mfma_f32_16x16x32_bf16(Al[ks].v, bh, acc[n], 0, 0, 0);
            }
        }
#pragma unroll
        for (int n = 0; n < 3; ++n) {                    // D row=(lane>>4)*4+r = timestep
            if (n == 2 && jj >= 8) continue;             // cols 40..47 padding
#pragma unroll
            for (int r = 0; r < 4; ++r)
                gb[((lane >> 4) * 4 + r) * 42 + n * 16 + jj] = acc[n][r];
        }
    };

    const int gvbase = rr * 676 + colb;

    stage(0, 0, 0);
    for (int wdw = 0; wdw < 13; ++wdw) {
        // ---- produce the window's 8 row-tiles (1-deep counted stage pipe) ----
        for (int r8 = 0; r8 < 8; ++r8) {
            const bool has_next = !(wdw == 12 && r8 == 7);
            if (has_next) {
                int nw = (r8 == 7) ? wdw + 1 : wdw;
                stage((r8 + 1) & 7, nw * 16, (r8 + 1) & 1);   // other buffer
                asm volatile("s_waitcnt vmcnt(5)" ::: "memory"); // current tile done
            } else {
                asm volatile("s_waitcnt vmcnt(0)" ::: "memory");
            }
            produce(&xb[r8 & 1][0], gbuf + r8 * 676);
        }
        // ---- recurrence: 8 rows in lockstep, 16 (or 8) steps ----
        const int nsteps = (wdw == 12) ? 8 : 16;
        for (int tt = 0; tt < nsteps; ++tt) {
            float gv[5];
#pragma unroll
            for (int q = 0; q < 5; ++q) gv[q] = gbuf[gvbase + tt * 42 + q] * LOG2E;
            float pre[5];
#pragma unroll
            for (int qp = 0; qp < 5; ++qp) {             // split dot: own + other half
                float a0 = gv[qp];
                float a1 = ho[0] * wo[qp][0];            // wait—keep 2 chains
                a0 = fmaf(hx[0], wx[qp][0], a0);
                a1 = fmaf(hx[1], wx[qp][1], a1);
                a0 = fmaf(ho[1], wo[qp][1], a0);
                a1 = fmaf(hx[2], wx[qp][2], a1);
                a0 = fmaf(ho[2], wo[qp][2], a0);
                a1 = fmaf(hx[3], wx[qp][3], a1);
                a0 = fmaf(ho[3], wo[qp][3], a0);
                a1 = fmaf(hx[4], wx[qp][4], a1);
                a0 = fmaf(ho[4], wo[qp][4], a0);
                pre[qp] = a0 + a1;
            }
#pragma unroll
            for (int qp = 0; qp < 5; ++qp) {
                float e  = exp2f(pre[qp]);               // e^(sA*pre)
                float sg = __builtin_amdgcn_rcpf(1.0f + e);
                float act = fmaf(sg, sM, sC);            // sigma / -2L*tanh
                int ai = __float_as_int(act);
                float a1d = __int_as_float(__builtin_amdgcn_mov_dpp(ai, 0xB1, 0xF, 0xF, true));
                float a2d = __int_as_float(__builtin_amdgcn_mov_dpp(ai, 0x4E, 0xF, 0xF, true));
                float a3d = __int_as_float(__builtin_amdgcn_mov_dpp(ai, 0x1B, 0xF, 0xF, true));
                C[qp] = fmaf(a1d, C[qp], act * a2d);     // valid at ty==0 lanes
                float e2 = exp2f(C[qp]);                 // e^(-2c)
                float th = fmaf(2.0f, __builtin_amdgcn_rcpf(1.0f + e2), -1.0f);
                float hn = a3d * th;                     // h = o*tanh(c), valid ty==0
                int hb = __builtin_amdgcn_mov_dpp(__float_as_int(hn), 0x00, 0xF, 0xF, true); // quad bcast ty0
                ho[qp] = __int_as_float(hb);
                hx[qp] = __int_as_float(__builtin_amdgcn_ds_swizzle(hb, 0x101F)); // lane^4: other half
            }
        }
    }

    if (ii == 0) {                                       // hf==0: ho=units 0-4, hx=5-9
        float o = lin_b[0];
#pragma unroll
        for (int q = 0; q < 5; ++q) o = fmaf(ho[q], lin_w[q], o);
#pragma unroll
        for (int q = 0; q < 5; ++q) o = fmaf(hx[q], lin_w[5 + q], o);
        out[b0 + rr] = o;
    }
}

extern "C" void kernel_launch(void* const* d_in, const int* in_sizes, int n_in,
                              void* d_out, int out_size, void* d_ws, size_t ws_size,
                              hipStream_t stream) {
    const float* x = (const float*)d_in[0];
    float* w   = (float*)d_ws;
    float* out = (float*)d_out;

    prep_kernel<<<20, 256, 0, stream>>>(
        (const float*)d_in[1], (const float*)d_in[2], (const float*)d_in[3],
        (const float*)d_in[4], (const float*)d_in[5], (const float*)d_in[6],
        (const float*)d_in[7], (const float*)d_in[8], (const float*)d_in[9], w);

    fused_kernel<<<Bsz / 8, 64, 0, stream>>>(
        x, w, (const float*)d_in[10], (const float*)d_in[11], out);
}